// Round 15
// baseline (165.730 us; speedup 1.0000x reference)
//
#include <hip/hip_runtime.h>
#include <math.h>

typedef unsigned short ushort_t;
typedef __bf16 bf16x8 __attribute__((ext_vector_type(8)));
typedef __bf16 bf16x4 __attribute__((ext_vector_type(4)));
typedef float f32x4 __attribute__((ext_vector_type(4)));

#define TWO_PI_F 6.283185307179586f

// ---- ws float-offset layout ----
#define WMT_OFF   0         // [296][512] f32 W_mod^T
#define PC_OFF    151552    // [1024][512] f32 per-b modulation constants
#define WT0P_OFF  675840    // 40960 ushort: GEMM0 W-frags [5 ks][16 nt][64 l][8 j]
#define WT1P_OFF  696320    // 98304 ushort: GEMM1 W-frags [12 ks][16 nt][64 l][8 j]

__device__ __forceinline__ ushort_t f2bf(float f) {
  unsigned int u = __float_as_uint(f);
  u += 0x7fffu + ((u >> 16) & 1u);
  return (ushort_t)(u >> 16);
}

// ---------------- pack: W_mod^T (f32) + MFMA W-fragment panels (bf16) ----------------
__global__ void pack_mfma_k(const float* __restrict__ W0,
                            const float* __restrict__ W1,
                            const float* __restrict__ W_mod,
                            float* __restrict__ WmT,
                            ushort_t* __restrict__ WT0p,
                            ushort_t* __restrict__ WT1p) {
  int i0 = blockIdx.x * blockDim.x + threadIdx.x;
  int stride = gridDim.x * blockDim.x;
  for (int idx = i0; idx < 296 * 512; idx += stride) {
    int c = idx >> 9, m = idx & 511;
    WmT[idx] = W_mod[m * 296 + c];
  }
  for (int e = i0; e < 40960; e += stride) {
    int j = e & 7, l = (e >> 3) & 63, nt = (e >> 9) & 15, ks = e >> 13;
    int k = ks * 32 + (l >> 4) * 8 + j;
    int n = nt * 16 + (l & 15);
    float v = 0.0f;
    if (k < 17) v = W0[n * 17 + k];
    else if (k >= 32) v = W_mod[n * 296 + 128 + (k - 32)];
    WT0p[e] = f2bf(v);
  }
  for (int e = i0; e < 98304; e += stride) {
    int j = e & 7, l = (e >> 3) & 63, nt = (e >> 9) & 15, ks = e >> 13;
    int k = ks * 32 + (l >> 4) * 8 + j;
    int n = nt * 16 + (l & 15);
    float v = (k < 256) ? W1[n * 256 + k]
                        : W_mod[(256 + n) * 296 + 128 + (k - 256)];
    WT1p[e] = f2bf(v);
  }
}

// ---------------- static encoder + per-b modulation consts (verified R1-R14) ----------------
__global__ void precompute_pc_k(const float* __restrict__ code,
                                const float* __restrict__ x_statics,
                                const int* __restrict__ dir_idx,
                                const float* __restrict__ WmT,
                                const float* __restrict__ b_mod,
                                const float* __restrict__ b0,
                                const float* __restrict__ b1,
                                const float* __restrict__ Bmat,
                                const float* __restrict__ Ws1,
                                const float* __restrict__ bs1,
                                const float* __restrict__ Ws2,
                                const float* __restrict__ bs2,
                                const float* __restrict__ dir_emb,
                                float* __restrict__ pc) {
  int b = blockIdx.x, t = threadIdx.x;  // 512 threads
  __shared__ float feats[32];
  __shared__ float h[64];
  __shared__ float se[40];
  __shared__ float cd[128];
  if (t < 16) {
    float p = TWO_PI_F * (x_statics[2 * b] * Bmat[t] + x_statics[2 * b + 1] * Bmat[16 + t]);
    feats[t] = sinf(p);
    feats[16 + t] = cosf(p);
  }
  if (t >= 128 && t < 256) cd[t - 128] = code[b * 128 + (t - 128)];
  __syncthreads();
  if (t < 64) {
    float a = bs1[t];
#pragma unroll
    for (int c = 0; c < 32; ++c) a = fmaf(feats[c], Ws1[t * 32 + c], a);
    h[t] = 0.5f * a * (1.0f + erff(a * 0.70710678118654752440f));
  }
  __syncthreads();
  if (t < 32) {
    float a = bs2[t];
#pragma unroll
    for (int c = 0; c < 64; ++c) a = fmaf(h[c], Ws2[t * 64 + c], a);
    se[t] = a;
  } else if (t < 40) {
    se[t] = dir_emb[dir_idx[b] * 8 + (t - 32)];
  }
  __syncthreads();
  float a = b_mod[t] + ((t < 256) ? b0[t] : b1[t - 256]);
  for (int c = 0; c < 128; ++c) a = fmaf(cd[c], WmT[c * 512 + t], a);
#pragma unroll
  for (int c = 0; c < 40; ++c) a = fmaf(se[c], WmT[(256 + c) * 512 + t], a);
  pc[b * 512 + t] = a;
}

// ---------------- main: MFMA FiLM MLP, 4 waves x (64r x 64c) ----------------
// R15 = R13 (163.9us best) minus one barrier:
//   pos moves to a separate posb (64 x 48B + 16B zero block; R4's verified
//   addressing), overlaid by psum (barrier-separated uses). pc0 is held in 4
//   float4 REGISTERS (frees 1KB LDS so 3 blocks/CU survive: 49152 + 3088 +
//   1024 = 53264 <= 54613). GEMM0 runs natural k-order 0..4; epilogue0's x0
//   writes touch rowbuf [0,512) which GEMM0 never reads -> the pos-protection
//   barrier is GONE (3 barriers/block instead of 4; ~400cy full-drain each).
// grid = 8192 (64 rows), block = 256 = 4 waves; wave wc owns n-cols
// [wc*64, wc*64+64); mt 0..3 covers the 64 t-rows. (256,3) cap; R13 used 80.
// rowbuf row (768B): [0,512) x0 (after ep0), [512,768) hs; XOR-swizzle
// ((row&7)<<4) on 16B chunks. Keeps R13's isolated-validated setprio (T5).
__global__ __launch_bounds__(256, 3) void film_mfma(
    const float* __restrict__ coords, const float* __restrict__ hs,
    const float* __restrict__ pc, const ushort_t* __restrict__ WT0p,
    const ushort_t* __restrict__ WT1p, const float* __restrict__ Wo,
    const float* __restrict__ bo, float* __restrict__ out) {
  __shared__ uint4 rowbuf4[49152 / 16];
  __shared__ uint4 posb4[3088 / 16];
  __shared__ float pcs1[256];
  char* rowbuf = (char*)rowbuf4;
  char* posb = (char*)posb4;
  float* psum = (float*)posb4;  // overlay: posb read only in GEMM0, psum written in ep1

  const int tid = threadIdx.x;
  const int wc = tid >> 6;
  const int l = tid & 63;
  const int l4 = l & 15;
  const int hi4 = l >> 4;
  const size_t row0 = (size_t)blockIdx.x * 64;
  const int b = blockIdx.x >> 3;

  // pc0 -> registers (issue early; 16B aligned since n0 % 4 == 0)
  float4 p40[4];
#pragma unroll
  for (int i = 0; i < 4; ++i)
    p40[i] = *(const float4*)&pc[(size_t)b * 512 + (wc * 4 + i) * 16 + hi4 * 4];
  pcs1[tid] = pc[(size_t)b * 512 + 256 + tid];

  // ---- stage hs -> rowbuf[row][512..768), bf16, swizzled ----
  {
    const float4* hsv = (const float4*)(hs + row0 * 128);
#pragma unroll
    for (int it = 0; it < 8; ++it) {
      int idx = it * 256 + tid;   // 2048 float4 = 64 rows x 32
      int r = idx >> 5, c4 = idx & 31;
      float4 v = hsv[idx];
      bf16x4 hb;
      hb[0] = (__bf16)v.x; hb[1] = (__bf16)v.y;
      hb[2] = (__bf16)v.z; hb[3] = (__bf16)v.w;
      int byte = (r * 768 + 512 + c4 * 8) ^ ((r & 7) << 4);
      *(uint2*)(rowbuf + byte) = __builtin_bit_cast(uint2, hb);
    }
  }
  // ---- stage pos -> posb[row*48 .. +48), k=0..23 (17 real + 7 zeros) ----
  if (tid < 64) {
    int row = tid;
    float c = coords[row0 + row];
    __bf16 pv[24];
    pv[0] = (__bf16)c;
    pv[1] = (__bf16)0.0f;  // sin(0*c)
    pv[9] = (__bf16)1.0f;  // cos(0*c)
#pragma unroll
    for (int f = 1; f < 8; ++f) {
      float s, co;
      __sincosf(1.25f * (float)f * c, &s, &co);
      pv[1 + f] = (__bf16)s;
      pv[9 + f] = (__bf16)co;
    }
#pragma unroll
    for (int k = 17; k < 24; ++k) pv[k] = (__bf16)0.0f;
#pragma unroll
    for (int s = 0; s < 3; ++s)
      *(uint4*)(posb + row * 48 + s * 16) = *(const uint4*)&pv[s * 8];
  } else if (tid < 72) {
    ((ushort_t*)(posb + 3072))[tid - 64] = 0;  // zero block for hi4==3 reads
  }

  // per-mt LDS addressing (row&7 == l4&7 since mt*16 ≡ 0 mod 8)
  const int swzU = (l4 & 7) << 4;
  int addrU[4];
  const char* addrP[4];
#pragma unroll
  for (int mt = 0; mt < 4; ++mt) {
    int row = mt * 16 + l4;
    addrU[mt] = row * 768 + hi4 * 16;
    addrP[mt] = posb + ((hi4 == 3) ? 3072 : row * 48 + hi4 * 16);
  }

  const uint4* Bb0 = (const uint4*)WT0p;
  const uint4* Bb1 = (const uint4*)WT1p;

  // prefetch GEMM0 ks=0 (pos) weight frags before the staging barrier
  uint4 wp[4];
#pragma unroll
  for (int i = 0; i < 4; ++i) wp[i] = Bb0[(0 * 16 + wc * 4 + i) * 64 + l];

  __syncthreads();  // B1: staging visible

  f32x4 acc[4][4];
#pragma unroll
  for (int mt = 0; mt < 4; ++mt)
#pragma unroll
    for (int i = 0; i < 4; ++i) acc[mt][i] = (f32x4){0.f, 0.f, 0.f, 0.f};

  // ---------------- GEMM0: K=160, natural k-order 0..4 (pos first), 1-deep W ----------------
#pragma unroll
  for (int ks = 0; ks < 5; ++ks) {
    bf16x8 w[4];
#pragma unroll
    for (int i = 0; i < 4; ++i) w[i] = __builtin_bit_cast(bf16x8, wp[i]);
    if (ks < 4) {
#pragma unroll
      for (int i = 0; i < 4; ++i) wp[i] = Bb0[((ks + 1) * 16 + wc * 4 + i) * 64 + l];
    }
#pragma unroll
    for (int mt = 0; mt < 4; ++mt) {
      bf16x8 u;
      if (ks == 0) {
        __builtin_memcpy(&u, addrP[mt], 16);
      } else {
        __builtin_memcpy(&u, rowbuf + ((addrU[mt] + 512 + (ks - 1) * 64) ^ swzU), 16);
      }
      __builtin_amdgcn_s_setprio(1);
#pragma unroll
      for (int i = 0; i < 4; ++i)
        acc[mt][i] = __builtin_amdgcn_mfma_f32_16x16x32_bf16(w[i], u, acc[mt][i], 0, 0, 0);
      __builtin_amdgcn_s_setprio(0);
    }
  }

  // prefetch GEMM1 step 0 weights; they land during epilogue0 + barrier
#pragma unroll
  for (int i = 0; i < 4; ++i) wp[i] = Bb1[(wc * 4 + i) * 64 + l];

  // ---- epilogue0 (NO barrier needed: GEMM0 never reads rowbuf [0,512)) ----
#pragma unroll
  for (int i = 0; i < 4; ++i) {
    int n0 = (wc * 4 + i) * 16 + hi4 * 4;
#pragma unroll
    for (int mt = 0; mt < 4; ++mt) {
      int t = mt * 16 + l4;
      bf16x4 hv;
      hv[0] = (__bf16)fmaxf(acc[mt][i][0] + p40[i].x, 0.f);
      hv[1] = (__bf16)fmaxf(acc[mt][i][1] + p40[i].y, 0.f);
      hv[2] = (__bf16)fmaxf(acc[mt][i][2] + p40[i].z, 0.f);
      hv[3] = (__bf16)fmaxf(acc[mt][i][3] + p40[i].w, 0.f);
      int byte = (t * 768 + n0 * 2) ^ ((t & 7) << 4);
      *(uint2*)(rowbuf + byte) = __builtin_bit_cast(uint2, hv);
    }
  }
  __syncthreads();  // B2: x0 visible to all waves

#pragma unroll
  for (int mt = 0; mt < 4; ++mt)
#pragma unroll
    for (int i = 0; i < 4; ++i) acc[mt][i] = (f32x4){0.f, 0.f, 0.f, 0.f};

  // ---------------- GEMM1: K=384 (x0 [0,512) then hs [512,768)), 1-deep W ----------------
#pragma unroll
  for (int ks = 0; ks < 12; ++ks) {
    bf16x8 w[4];
#pragma unroll
    for (int i = 0; i < 4; ++i) w[i] = __builtin_bit_cast(bf16x8, wp[i]);
    if (ks < 11) {
#pragma unroll
      for (int i = 0; i < 4; ++i) wp[i] = Bb1[((ks + 1) * 16 + wc * 4 + i) * 64 + l];
    }
#pragma unroll
    for (int mt = 0; mt < 4; ++mt) {
      bf16x8 u;
      __builtin_memcpy(&u, rowbuf + ((addrU[mt] + ks * 64) ^ swzU), 16);
      __builtin_amdgcn_s_setprio(1);
#pragma unroll
      for (int i = 0; i < 4; ++i)
        acc[mt][i] = __builtin_amdgcn_mfma_f32_16x16x32_bf16(w[i], u, acc[mt][i], 0, 0, 0);
      __builtin_amdgcn_s_setprio(0);
    }
  }

  // ---- epilogue1: relu(acc + pc1) . Wo; reduce 16 n per lane + 2 shfl -> psum ----
  {
    float4 p4[4], w4[4];
#pragma unroll
    for (int i = 0; i < 4; ++i) {
      int n0 = (wc * 4 + i) * 16 + hi4 * 4;
      p4[i] = *(const float4*)&pcs1[n0];
      w4[i] = ((const float4*)Wo)[(wc * 4 + i) * 4 + hi4];
    }
#pragma unroll
    for (int mt = 0; mt < 4; ++mt) {
      float s = 0.f;
#pragma unroll
      for (int i = 0; i < 4; ++i) {
        s += fmaxf(acc[mt][i][0] + p4[i].x, 0.f) * w4[i].x;
        s += fmaxf(acc[mt][i][1] + p4[i].y, 0.f) * w4[i].y;
        s += fmaxf(acc[mt][i][2] + p4[i].z, 0.f) * w4[i].z;
        s += fmaxf(acc[mt][i][3] + p4[i].w, 0.f) * w4[i].w;
      }
      s += __shfl_xor(s, 16);
      s += __shfl_xor(s, 32);
      if (hi4 == 0) psum[wc * 64 + mt * 16 + l4] = s;  // posb overlay (pos dead since B2)
    }
  }
  __syncthreads();  // B3: psum visible
  if (tid < 64) {
    float s = bo[0] + psum[tid] + psum[64 + tid] + psum[128 + tid] + psum[192 + tid];
    out[row0 + tid] = s;
  }
}

extern "C" void kernel_launch(void* const* d_in, const int* in_sizes, int n_in,
                              void* d_out, int out_size, void* d_ws, size_t ws_size,
                              hipStream_t stream) {
  (void)in_sizes; (void)n_in; (void)out_size; (void)ws_size;
  const float* coords    = (const float*)d_in[0];
  const float* code      = (const float*)d_in[1];
  const float* hs        = (const float*)d_in[2];
  const float* x_statics = (const float*)d_in[3];
  const int*   dir_idx   = (const int*)d_in[4];
  const float* W_mod     = (const float*)d_in[5];
  const float* b_mod     = (const float*)d_in[6];
  const float* W0        = (const float*)d_in[7];
  const float* b0        = (const float*)d_in[8];
  const float* W1        = (const float*)d_in[9];
  const float* b1        = (const float*)d_in[10];
  const float* Wo        = (const float*)d_in[11];
  const float* bo        = (const float*)d_in[12];
  const float* Bmat      = (const float*)d_in[13];
  const float* Ws1       = (const float*)d_in[14];
  const float* bs1       = (const float*)d_in[15];
  const float* Ws2       = (const float*)d_in[16];
  const float* bs2       = (const float*)d_in[17];
  const float* dir_emb   = (const float*)d_in[18];
  float* out = (float*)d_out;
  float* wsf = (float*)d_ws;

  float*    WmT  = wsf + WMT_OFF;
  float*    pc   = wsf + PC_OFF;
  ushort_t* WT0p = (ushort_t*)(wsf + WT0P_OFF);
  ushort_t* WT1p = (ushort_t*)(wsf + WT1P_OFF);

  hipLaunchKernelGGL(pack_mfma_k, dim3(1024), dim3(256), 0, stream,
                     W0, W1, W_mod, WmT, WT0p, WT1p);
  hipLaunchKernelGGL(precompute_pc_k, dim3(1024), dim3(512), 0, stream,
                     code, x_statics, dir_idx, WmT, b_mod, b0, b1,
                     Bmat, Ws1, bs1, Ws2, bs2, dir_emb, pc);
  hipLaunchKernelGGL(film_mfma, dim3(8192), dim3(256), 0, stream,
                     coords, hs, pc, WT0p, WT1p, Wo, bo, out);
}

// Round 16
// 164.874 us; speedup vs baseline: 1.0052x; 1.0052x over previous
//
#include <hip/hip_runtime.h>
#include <math.h>

typedef unsigned short ushort_t;
typedef __bf16 bf16x8 __attribute__((ext_vector_type(8)));
typedef __bf16 bf16x4 __attribute__((ext_vector_type(4)));
typedef float f32x4 __attribute__((ext_vector_type(4)));

#define TWO_PI_F 6.283185307179586f

// ---- ws float-offset layout ----
#define WMT_OFF   0         // [296][512] f32 W_mod^T
#define PC_OFF    151552    // [1024][512] f32 per-b modulation constants
#define WT0P_OFF  675840    // 40960 ushort: GEMM0 W-frags [5 ks][16 nt][64 l][8 j]
#define WT1P_OFF  696320    // 98304 ushort: GEMM1 W-frags [12 ks][16 nt][64 l][8 j]

__device__ __forceinline__ ushort_t f2bf(float f) {
  unsigned int u = __float_as_uint(f);
  u += 0x7fffu + ((u >> 16) & 1u);
  return (ushort_t)(u >> 16);
}

// ---------------- pack: W_mod^T (f32) + MFMA W-fragment panels (bf16) ----------------
__global__ void pack_mfma_k(const float* __restrict__ W0,
                            const float* __restrict__ W1,
                            const float* __restrict__ W_mod,
                            float* __restrict__ WmT,
                            ushort_t* __restrict__ WT0p,
                            ushort_t* __restrict__ WT1p) {
  int i0 = blockIdx.x * blockDim.x + threadIdx.x;
  int stride = gridDim.x * blockDim.x;
  for (int idx = i0; idx < 296 * 512; idx += stride) {
    int c = idx >> 9, m = idx & 511;
    WmT[idx] = W_mod[m * 296 + c];
  }
  for (int e = i0; e < 40960; e += stride) {
    int j = e & 7, l = (e >> 3) & 63, nt = (e >> 9) & 15, ks = e >> 13;
    int k = ks * 32 + (l >> 4) * 8 + j;
    int n = nt * 16 + (l & 15);
    float v = 0.0f;
    if (k < 17) v = W0[n * 17 + k];
    else if (k >= 32) v = W_mod[n * 296 + 128 + (k - 32)];
    WT0p[e] = f2bf(v);
  }
  for (int e = i0; e < 98304; e += stride) {
    int j = e & 7, l = (e >> 3) & 63, nt = (e >> 9) & 15, ks = e >> 13;
    int k = ks * 32 + (l >> 4) * 8 + j;
    int n = nt * 16 + (l & 15);
    float v = (k < 256) ? W1[n * 256 + k]
                        : W_mod[(256 + n) * 296 + 128 + (k - 256)];
    WT1p[e] = f2bf(v);
  }
}

// ---------------- static encoder + per-b modulation consts (verified R1-R15) ----------------
__global__ void precompute_pc_k(const float* __restrict__ code,
                                const float* __restrict__ x_statics,
                                const int* __restrict__ dir_idx,
                                const float* __restrict__ WmT,
                                const float* __restrict__ b_mod,
                                const float* __restrict__ b0,
                                const float* __restrict__ b1,
                                const float* __restrict__ Bmat,
                                const float* __restrict__ Ws1,
                                const float* __restrict__ bs1,
                                const float* __restrict__ Ws2,
                                const float* __restrict__ bs2,
                                const float* __restrict__ dir_emb,
                                float* __restrict__ pc) {
  int b = blockIdx.x, t = threadIdx.x;  // 512 threads
  __shared__ float feats[32];
  __shared__ float h[64];
  __shared__ float se[40];
  __shared__ float cd[128];
  if (t < 16) {
    float p = TWO_PI_F * (x_statics[2 * b] * Bmat[t] + x_statics[2 * b + 1] * Bmat[16 + t]);
    feats[t] = sinf(p);
    feats[16 + t] = cosf(p);
  }
  if (t >= 128 && t < 256) cd[t - 128] = code[b * 128 + (t - 128)];
  __syncthreads();
  if (t < 64) {
    float a = bs1[t];
#pragma unroll
    for (int c = 0; c < 32; ++c) a = fmaf(feats[c], Ws1[t * 32 + c], a);
    h[t] = 0.5f * a * (1.0f + erff(a * 0.70710678118654752440f));
  }
  __syncthreads();
  if (t < 32) {
    float a = bs2[t];
#pragma unroll
    for (int c = 0; c < 64; ++c) a = fmaf(h[c], Ws2[t * 64 + c], a);
    se[t] = a;
  } else if (t < 40) {
    se[t] = dir_emb[dir_idx[b] * 8 + (t - 32)];
  }
  __syncthreads();
  float a = b_mod[t] + ((t < 256) ? b0[t] : b1[t - 256]);
  for (int c = 0; c < 128; ++c) a = fmaf(cd[c], WmT[c * 512 + t], a);
#pragma unroll
  for (int c = 0; c < 40; ++c) a = fmaf(se[c], WmT[(256 + c) * 512 + t], a);
  pc[b * 512 + t] = a;
}

// ---------------- main: MFMA FiLM MLP, 4 waves x (64r x 64c) ----------------
// FINAL = R13 (163.9us best measured): R10 structure + isolated T5 setprio.
// 146 GFLOP / 163.9us = 891 TF bf16 = 36% of dense peak -- at the documented
// plain-HIP 2-barrier structural ceiling (m97-class 874-912 TF). All pipes
// 33-40% (overlap-bound, none saturated); scheduling variants (W-dbuf, u-dbuf,
// 2-deep prefetch, barrier-removal) all neutral/negative; deeper pipelining
// can't amortize over K=160/384 with the GEMM0->GEMM1 dependency barrier.
// grid = 8192 (64 rows), block = 256 = 4 waves; wave wc owns n-cols
// [wc*64, wc*64+64) via 4 W-frags; mt 0..3 covers the 64 t-rows.
// LDS 52224 -> 3 blocks/CU. (256,3) -> 170-reg cap; measured 80, no spill.
// rowbuf row (768B), XOR-swizzle ((row&7)<<4) on 16B chunks:
//   GEMM0 k-order {1,2,3,4,0}: pos (bytes [0,64)) read last; barrier;
//   epilogue0 overwrites [0,512) with x0; GEMM1 reads ks*64, ks=0..11.
__global__ __launch_bounds__(256, 3) void film_mfma(
    const float* __restrict__ coords, const float* __restrict__ hs,
    const float* __restrict__ pc, const ushort_t* __restrict__ WT0p,
    const ushort_t* __restrict__ WT1p, const float* __restrict__ Wo,
    const float* __restrict__ bo, float* __restrict__ out) {
  __shared__ uint4 rowbuf4[49152 / 16];
  __shared__ float pcs[512];
  __shared__ float psum[256];  // [wc 4][row 64]
  char* rowbuf = (char*)rowbuf4;

  const int tid = threadIdx.x;
  const int wc = tid >> 6;
  const int l = tid & 63;
  const int l4 = l & 15;
  const int hi4 = l >> 4;
  const size_t row0 = (size_t)blockIdx.x * 64;
  const int b = blockIdx.x >> 3;

  pcs[tid] = pc[(size_t)b * 512 + tid];
  pcs[tid + 256] = pc[(size_t)b * 512 + 256 + tid];

  // ---- stage hs -> rowbuf[row][512..768), bf16, swizzled ----
  {
    const float4* hsv = (const float4*)(hs + row0 * 128);
#pragma unroll
    for (int it = 0; it < 8; ++it) {
      int idx = it * 256 + tid;   // 2048 float4 = 64 rows x 32
      int r = idx >> 5, c4 = idx & 31;
      float4 v = hsv[idx];
      bf16x4 hb;
      hb[0] = (__bf16)v.x; hb[1] = (__bf16)v.y;
      hb[2] = (__bf16)v.z; hb[3] = (__bf16)v.w;
      int byte = (r * 768 + 512 + c4 * 8) ^ ((r & 7) << 4);
      *(uint2*)(rowbuf + byte) = __builtin_bit_cast(uint2, hb);
    }
  }
  // ---- stage pos -> rowbuf[row][0..64), bf16, pre-swizzled 16B chunks ----
  if (tid < 64) {
    int row = tid;
    float c = coords[row0 + row];
    __bf16 pv[32];
    pv[0] = (__bf16)c;
    pv[1] = (__bf16)0.0f;  // sin(0*c)
    pv[9] = (__bf16)1.0f;  // cos(0*c)
#pragma unroll
    for (int f = 1; f < 8; ++f) {
      float s, co;
      __sincosf(1.25f * (float)f * c, &s, &co);
      pv[1 + f] = (__bf16)s;
      pv[9 + f] = (__bf16)co;
    }
#pragma unroll
    for (int k = 17; k < 32; ++k) pv[k] = (__bf16)0.0f;
    int base = row * 768, swzp = (row & 7) << 4;
#pragma unroll
    for (int s = 0; s < 4; ++s)
      *(uint4*)(rowbuf + ((base + s * 16) ^ swzp)) = *(const uint4*)&pv[s * 8];
  }

  // per-mt LDS addressing (row&7 == l4&7 since mt*16 ≡ 0 mod 8)
  const int swzU = (l4 & 7) << 4;
  int addrU[4];
#pragma unroll
  for (int mt = 0; mt < 4; ++mt)
    addrU[mt] = (mt * 16 + l4) * 768 + hi4 * 16;

  const uint4* Bb0 = (const uint4*)WT0p;
  const uint4* Bb1 = (const uint4*)WT1p;

  // prefetch GEMM0 step 0 (ks=1) weight frags before the staging barrier
  uint4 wp[4];
#pragma unroll
  for (int i = 0; i < 4; ++i) wp[i] = Bb0[(1 * 16 + wc * 4 + i) * 64 + l];

  __syncthreads();

  f32x4 acc[4][4];
#pragma unroll
  for (int mt = 0; mt < 4; ++mt)
#pragma unroll
    for (int i = 0; i < 4; ++i) acc[mt][i] = (f32x4){0.f, 0.f, 0.f, 0.f};

  // ---------------- GEMM0: K=160, k-order {1,2,3,4,0}, W double-buffered ----------------
#pragma unroll
  for (int kk = 0; kk < 5; ++kk) {
    const int ks = (kk < 4) ? (kk + 1) : 0;
    bf16x8 w[4];
#pragma unroll
    for (int i = 0; i < 4; ++i) w[i] = __builtin_bit_cast(bf16x8, wp[i]);
    if (kk < 4) {
      const int ksn = (kk < 3) ? (kk + 2) : 0;
#pragma unroll
      for (int i = 0; i < 4; ++i) wp[i] = Bb0[(ksn * 16 + wc * 4 + i) * 64 + l];
    }
#pragma unroll
    for (int mt = 0; mt < 4; ++mt) {
      bf16x8 u;
      int off = (ks == 0) ? addrU[mt] : (addrU[mt] + 512 + (ks - 1) * 64);
      __builtin_memcpy(&u, rowbuf + (off ^ swzU), 16);
      __builtin_amdgcn_s_setprio(1);
#pragma unroll
      for (int i = 0; i < 4; ++i)
        acc[mt][i] = __builtin_amdgcn_mfma_f32_16x16x32_bf16(w[i], u, acc[mt][i], 0, 0, 0);
      __builtin_amdgcn_s_setprio(0);
    }
  }

  // prefetch GEMM1 step 0 weights; they land during epilogue0 + barriers
#pragma unroll
  for (int i = 0; i < 4; ++i) wp[i] = Bb1[(wc * 4 + i) * 64 + l];

  __syncthreads();  // all pos reads done before x0 overwrites [0,512)

  // ---- epilogue0: relu(acc + pc0) -> x0 bf16, packed b64 writes ----
#pragma unroll
  for (int i = 0; i < 4; ++i) {
    int n0 = (wc * 4 + i) * 16 + hi4 * 4;
    float4 p4 = *(const float4*)&pcs[n0];
#pragma unroll
    for (int mt = 0; mt < 4; ++mt) {
      int t = mt * 16 + l4;
      bf16x4 hv;
      hv[0] = (__bf16)fmaxf(acc[mt][i][0] + p4.x, 0.f);
      hv[1] = (__bf16)fmaxf(acc[mt][i][1] + p4.y, 0.f);
      hv[2] = (__bf16)fmaxf(acc[mt][i][2] + p4.z, 0.f);
      hv[3] = (__bf16)fmaxf(acc[mt][i][3] + p4.w, 0.f);
      int byte = (t * 768 + n0 * 2) ^ ((t & 7) << 4);
      *(uint2*)(rowbuf + byte) = __builtin_bit_cast(uint2, hv);
    }
  }
  __syncthreads();

#pragma unroll
  for (int mt = 0; mt < 4; ++mt)
#pragma unroll
    for (int i = 0; i < 4; ++i) acc[mt][i] = (f32x4){0.f, 0.f, 0.f, 0.f};

  // ---------------- GEMM1: K=384 (x0 [0,512) then hs [512,768)), W double-buffered ----------------
#pragma unroll
  for (int ks = 0; ks < 12; ++ks) {
    bf16x8 w[4];
#pragma unroll
    for (int i = 0; i < 4; ++i) w[i] = __builtin_bit_cast(bf16x8, wp[i]);
    if (ks < 11) {
#pragma unroll
      for (int i = 0; i < 4; ++i) wp[i] = Bb1[((ks + 1) * 16 + wc * 4 + i) * 64 + l];
    }
#pragma unroll
    for (int mt = 0; mt < 4; ++mt) {
      bf16x8 u;
      __builtin_memcpy(&u, rowbuf + ((addrU[mt] + ks * 64) ^ swzU), 16);
      __builtin_amdgcn_s_setprio(1);
#pragma unroll
      for (int i = 0; i < 4; ++i)
        acc[mt][i] = __builtin_amdgcn_mfma_f32_16x16x32_bf16(w[i], u, acc[mt][i], 0, 0, 0);
      __builtin_amdgcn_s_setprio(0);
    }
  }

  // ---- epilogue1: relu(acc + pc1) . Wo; reduce 16 n per lane + 2 shfl -> psum ----
  {
    float4 p4[4], w4[4];
#pragma unroll
    for (int i = 0; i < 4; ++i) {
      int n0 = (wc * 4 + i) * 16 + hi4 * 4;
      p4[i] = *(const float4*)&pcs[256 + n0];
      w4[i] = ((const float4*)Wo)[(wc * 4 + i) * 4 + hi4];
    }
#pragma unroll
    for (int mt = 0; mt < 4; ++mt) {
      float s = 0.f;
#pragma unroll
      for (int i = 0; i < 4; ++i) {
        s += fmaxf(acc[mt][i][0] + p4[i].x, 0.f) * w4[i].x;
        s += fmaxf(acc[mt][i][1] + p4[i].y, 0.f) * w4[i].y;
        s += fmaxf(acc[mt][i][2] + p4[i].z, 0.f) * w4[i].z;
        s += fmaxf(acc[mt][i][3] + p4[i].w, 0.f) * w4[i].w;
      }
      s += __shfl_xor(s, 16);
      s += __shfl_xor(s, 32);
      if (hi4 == 0) psum[wc * 64 + mt * 16 + l4] = s;
    }
  }
  __syncthreads();
  if (tid < 64) {
    float s = bo[0] + psum[tid] + psum[64 + tid] + psum[128 + tid] + psum[192 + tid];
    out[row0 + tid] = s;
  }
}

extern "C" void kernel_launch(void* const* d_in, const int* in_sizes, int n_in,
                              void* d_out, int out_size, void* d_ws, size_t ws_size,
                              hipStream_t stream) {
  (void)in_sizes; (void)n_in; (void)out_size; (void)ws_size;
  const float* coords    = (const float*)d_in[0];
  const float* code      = (const float*)d_in[1];
  const float* hs        = (const float*)d_in[2];
  const float* x_statics = (const float*)d_in[3];
  const int*   dir_idx   = (const int*)d_in[4];
  const float* W_mod     = (const float*)d_in[5];
  const float* b_mod     = (const float*)d_in[6];
  const float* W0        = (const float*)d_in[7];
  const float* b0        = (const float*)d_in[8];
  const float* W1        = (const float*)d_in[9];
  const float* b1        = (const float*)d_in[10];
  const float* Wo        = (const float*)d_in[11];
  const float* bo        = (const float*)d_in[12];
  const float* Bmat      = (const float*)d_in[13];
  const float* Ws1       = (const float*)d_in[14];
  const float* bs1       = (const float*)d_in[15];
  const float* Ws2       = (const float*)d_in[16];
  const float* bs2       = (const float*)d_in[17];
  const float* dir_emb   = (const float*)d_in[18];
  float* out = (float*)d_out;
  float* wsf = (float*)d_ws;

  float*    WmT  = wsf + WMT_OFF;
  float*    pc   = wsf + PC_OFF;
  ushort_t* WT0p = (ushort_t*)(wsf + WT0P_OFF);
  ushort_t* WT1p = (ushort_t*)(wsf + WT1P_OFF);

  hipLaunchKernelGGL(pack_mfma_k, dim3(1024), dim3(256), 0, stream,
                     W0, W1, W_mod, WmT, WT0p, WT1p);
  hipLaunchKernelGGL(precompute_pc_k, dim3(1024), dim3(512), 0, stream,
                     code, x_statics, dir_idx, WmT, b_mod, b0, b1,
                     Bmat, Ws1, bs1, Ws2, bs2, dir_emb, pc);
  hipLaunchKernelGGL(film_mfma, dim3(8192), dim3(256), 0, stream,
                     coords, hs, pc, WT0p, WT1p, Wo, bo, out);
}